// Round 4
// baseline (1352.854 us; speedup 1.0000x reference)
//
#include <hip/hip_runtime.h>
#include <math.h>

#define BATCH 32768
#define DIM   512
#define NCODE 8192
#define DECAYF 0.995f
#define OMDF   0.005f
#define EPSF   1e-8f
#define MARGIN 8e-3f
#define MAXFLAG 2048
#define MAXTILE 12

typedef _Float16 half8 __attribute__((ext_vector_type(8)));
typedef _Float16 half4 __attribute__((ext_vector_type(4)));
typedef float f32x4 __attribute__((ext_vector_type(4)));

// ---------------- workspace layout (bytes) ----------------
#define OFF_SCAL   0        // double scal[8]: [0]=n_sum [1]=counts_sum
#define OFF_CNT    64       // int cnt
#define OFF_COUNTS 128      // int counts[NCODE]
#define OFF_ER     32896    // float er[NCODE]
#define OFF_IDX    65664    // int idxs[BATCH]
#define OFF_LOSS   196736   // double loss_part[4096]
#define OFF_FROW   229504   // int frow[MAXFLAG]
#define OFF_NFT    237696   // int nft[MAXFLAG]
#define OFF_FTILE  245888   // int ftile[MAXFLAG*MAXTILE]
#define OFF_RVAL   344192   // float rval[MAXFLAG*MAXTILE]
#define OFF_RIDX   442496   // int ridx[MAXFLAG*MAXTILE]
#define OFF_EH     540800   // _Float16 eh[NCODE*DIM]  (8 MB)
#define NLOSSBLK   4096

__device__ inline void atomAddD(double* p, double v){ unsafeAtomicAdd(p, v); }

// ---------- prep: er[k]=1/(||e_k||+eps), eh = fp16(e*er) ----------
__global__ __launch_bounds__(256) void k_prep_e(const float* __restrict__ emb,
                                                float* __restrict__ er,
                                                _Float16* __restrict__ eh) {
  int row = blockIdx.x * 4 + (threadIdx.x >> 6);
  int l = threadIdx.x & 63;
  const float4* p = (const float4*)(emb + (size_t)row * DIM);
  float4 a = p[l], b = p[l + 64];
  float s = a.x*a.x + a.y*a.y + a.z*a.z + a.w*a.w
          + b.x*b.x + b.y*b.y + b.z*b.z + b.w*b.w;
  #pragma unroll
  for (int off = 32; off > 0; off >>= 1) s += __shfl_down(s, off);
  s = __shfl(s, 0);
  float inv = 1.0f / (sqrtf(s) + EPSF);
  if (l == 0) er[row] = inv;
  half4 ha = { (_Float16)(a.x*inv), (_Float16)(a.y*inv), (_Float16)(a.z*inv), (_Float16)(a.w*inv) };
  half4 hb = { (_Float16)(b.x*inv), (_Float16)(b.y*inv), (_Float16)(b.z*inv), (_Float16)(b.w*inv) };
  *(half4*)(eh + (size_t)row * DIM + l * 4) = ha;
  *(half4*)(eh + (size_t)row * DIM + 256 + l * 4) = hb;
}

// ---------- prep: zh = fp16(z) split across out5/out7 regions ----------
__global__ __launch_bounds__(256) void k_prep_z(const float* __restrict__ z,
                                                _Float16* __restrict__ z5,
                                                _Float16* __restrict__ z7) {
  size_t base = ((size_t)blockIdx.x * 256 + threadIdx.x) * 8;
  const float4* zp = (const float4*)(z + base);
  float4 a = zp[0], b = zp[1];
  half8 h = { (_Float16)a.x, (_Float16)a.y, (_Float16)a.z, (_Float16)a.w,
              (_Float16)b.x, (_Float16)b.y, (_Float16)b.z, (_Float16)b.w };
  _Float16* dst = (base < (size_t)16384 * 512) ? (z5 + base)
                                               : (z7 + (base - (size_t)16384 * 512));
  *(half8*)dst = h;
}

// ---------- coarse fp16 MFMA GEMM + per-row top-2 per 128-col tile ----------
// L2-direct variant: NO LDS staging, NO barriers in the K-loop.  The B matrix
// (eh, 8 MB) is L2-resident and A (zh, 32 MB) is L3-resident, so MFMA
// fragments are loaded straight from global memory: lane (c16,quad) of each
// wave loads the 16 aligned bytes at row(c16)*1024 + kk*64 + quad*16 — a
// 16x64B coalesced pattern per instruction.  2-deep register pipeline
// (a0/b0, a1/b1) hides L2-hit latency under MFMAs; full unroll folds all
// K-offsets ((kk)*64 B <= 960) into load immediates.  Fragment values and
// accumulation order are bit-identical to the LDS-staged version, so
// c1v/c2v/c1i and all downstream flag/refine behavior are unchanged.
__global__ __launch_bounds__(256) void k_coarse(const _Float16* __restrict__ eh,
                                                const _Float16* __restrict__ z5,
                                                const _Float16* __restrict__ z7,
                                                float* __restrict__ c1v,
                                                float* __restrict__ c2v,
                                                int* __restrict__ c1i) {
  __shared__ float ev1[2][128];
  __shared__ float ev2[2][128];
  __shared__ int   ei1[2][128];

  const int t = threadIdx.x, w = t >> 6, lane = t & 63;
  const int quad = lane >> 4, c16 = lane & 15;
  const int row0 = blockIdx.x * 128;
  const int by = blockIdx.y, col0 = by * 128;
  const int m0 = (w & 1) * 64, n0 = (w >> 1) * 64;
  const _Float16* zbase = (row0 < 16384) ? z5 : (z7 - (size_t)16384 * 512);

  // per-lane fragment base pointers: A rows m0+i*16+c16, B cols n0+j*16+c16,
  // k-offset quad*8 halfs within each 32-half K-step.
  const _Float16* ap[4]; const _Float16* bp[4];
  #pragma unroll
  for (int i = 0; i < 4; i++) {
    ap[i] = zbase + (size_t)(row0 + m0 + i * 16 + c16) * 512 + quad * 8;
    bp[i] = eh    + (size_t)(col0 + n0 + i * 16 + c16) * 512 + quad * 8;
  }

  f32x4 acc[4][4];
  #pragma unroll
  for (int i = 0; i < 4; i++)
    #pragma unroll
    for (int j = 0; j < 4; j++) { acc[i][j][0]=0.f; acc[i][j][1]=0.f; acc[i][j][2]=0.f; acc[i][j][3]=0.f; }

  half8 a0[4], b0[4], a1[4], b1[4];
  #pragma unroll
  for (int i = 0; i < 4; i++) { a0[i] = *(const half8*)(ap[i]); b0[i] = *(const half8*)(bp[i]); }

  #pragma unroll
  for (int kk = 0; kk < 16; kk += 2) {
    // issue loads for step kk+1 before computing step kk
    #pragma unroll
    for (int i = 0; i < 4; i++) {
      a1[i] = *(const half8*)(ap[i] + (kk + 1) * 32);
      b1[i] = *(const half8*)(bp[i] + (kk + 1) * 32);
    }
    #pragma unroll
    for (int i = 0; i < 4; i++)
      #pragma unroll
      for (int j = 0; j < 4; j++)
        acc[i][j] = __builtin_amdgcn_mfma_f32_16x16x32_f16(a0[i], b0[j], acc[i][j], 0, 0, 0);
    if (kk + 2 < 16) {
      #pragma unroll
      for (int i = 0; i < 4; i++) {
        a0[i] = *(const half8*)(ap[i] + (kk + 2) * 32);
        b0[i] = *(const half8*)(bp[i] + (kk + 2) * 32);
      }
    }
    #pragma unroll
    for (int i = 0; i < 4; i++)
      #pragma unroll
      for (int j = 0; j < 4; j++)
        acc[i][j] = __builtin_amdgcn_mfma_f32_16x16x32_f16(a1[i], b1[j], acc[i][j], 0, 0, 0);
  }

  // epilogue: per-row top-2 over this block's 128 cols (unchanged)
  const int h = w >> 1;
  #pragma unroll
  for (int i = 0; i < 4; i++) {
    #pragma unroll
    for (int r = 0; r < 4; r++) {
      float v1 = acc[i][0][r];
      int   i1 = col0 + n0 + c16;
      float v2 = -3.0e38f;
      #pragma unroll
      for (int j = 1; j < 4; j++) {
        float v = acc[i][j][r];
        int ix = col0 + n0 + j * 16 + c16;
        if (v > v1) { v2 = fmaxf(v2, v1); v1 = v; i1 = ix; }
        else        { v2 = fmaxf(v2, v); }
      }
      #pragma unroll
      for (int m = 1; m < 16; m <<= 1) {
        float o1 = __shfl_xor(v1, m);
        float o2 = __shfl_xor(v2, m);
        int   oi = __shfl_xor(i1, m);
        if (o1 > v1 || (o1 == v1 && oi < i1)) { v2 = fmaxf(v1, o2); v1 = o1; i1 = oi; }
        else                                  { v2 = fmaxf(v2, o1); }
      }
      if (c16 == 0) {
        int rl = (w & 1) * 64 + i * 16 + quad * 4 + r;
        ev1[h][rl] = v1; ev2[h][rl] = v2; ei1[h][rl] = i1;
      }
    }
  }
  __syncthreads();
  if (t < 128) {
    float a1v = ev1[0][t], a2v = ev2[0][t]; int ai = ei1[0][t];
    float b1v = ev1[1][t], b2v = ev2[1][t]; int bi = ei1[1][t];
    float v1, v2; int i1;
    if (b1v > a1v || (b1v == a1v && bi < ai)) { v1 = b1v; i1 = bi; v2 = fmaxf(a1v, b2v); }
    else                                      { v1 = a1v; i1 = ai; v2 = fmaxf(a2v, b1v); }
    size_t o = (size_t)by * BATCH + row0 + t;
    c1v[o] = v1; c2v[o] = v2; c1i[o] = i1;
  }
}

// ---------- combine 64 tiles/row, margin test, flag list ----------
__global__ __launch_bounds__(256) void k_combine(const float* __restrict__ c1v,
                                                 const float* __restrict__ c2v,
                                                 const int* __restrict__ c1i,
                                                 int* __restrict__ idxs,
                                                 float* __restrict__ out3,
                                                 int* __restrict__ cnt,
                                                 int* __restrict__ frow,
                                                 int* __restrict__ nft,
                                                 int* __restrict__ ftile) {
  int row = blockIdx.x * 256 + threadIdx.x;
  float v1 = -3.0e38f, v2 = -3.0e38f; int i1 = 0;
  for (int ti = 0; ti < 64; ti++) {
    size_t o = (size_t)ti * BATCH + row;
    float a = c1v[o]; float a2 = c2v[o]; int ai = c1i[o];
    if (a > v1 || (a == v1 && ai < i1)) { v2 = fmaxf(v1, a2); v1 = a; i1 = ai; }
    else                                { v2 = fmaxf(v2, a); }
  }
  idxs[row] = i1;
  out3[row] = (float)i1;
  if (v1 - v2 < MARGIN) {
    int fid = atomicAdd(cnt, 1);
    if (fid < MAXFLAG) {
      frow[fid] = row;
      int jj = 0;
      for (int ti = 0; ti < 64; ti++) {
        if (c1v[(size_t)ti * BATCH + row] >= v1 - MARGIN && jj < MAXTILE)
          ftile[fid * MAXTILE + jj++] = ti;
      }
      nft[fid] = jj;
    }
  }
}

// ---------- exact fp32 refine of qualifying tiles for flagged rows ----------
__global__ __launch_bounds__(256) void k_refine(const float* __restrict__ z,
                                                const float* __restrict__ emb,
                                                const float* __restrict__ er,
                                                const int* __restrict__ cnt,
                                                const int* __restrict__ frow,
                                                const int* __restrict__ nft,
                                                const int* __restrict__ ftile,
                                                float* __restrict__ rval,
                                                int* __restrict__ ridx) {
  __shared__ float zl[512];
  __shared__ float rv[128];
  __shared__ int   ri[128];
  int fid = blockIdx.x;
  int m = cnt[0]; if (m > MAXFLAG) m = MAXFLAG;
  if (fid >= m) return;
  int t = threadIdx.x;
  int row = frow[fid];
  if (t < 128) ((float4*)zl)[t] = *(const float4*)(z + (size_t)row * 512 + t * 4);
  __syncthreads();
  int n = nft[fid];
  for (int jj = 0; jj < n; jj++) {
    int ti = ftile[fid * MAXTILE + jj];
    if (t < 128) {
      int code = ti * 128 + t;
      const float4* ep = (const float4*)(emb + (size_t)code * 512);
      const float4* zp = (const float4*)zl;
      float a0 = 0.f, a1 = 0.f, a2 = 0.f, a3 = 0.f;
      #pragma unroll 8
      for (int d = 0; d < 128; d++) {
        float4 e4 = ep[d]; float4 z4 = zp[d];
        a0 = fmaf(e4.x, z4.x, a0); a1 = fmaf(e4.y, z4.y, a1);
        a2 = fmaf(e4.z, z4.z, a2); a3 = fmaf(e4.w, z4.w, a3);
      }
      rv[t] = ((a0 + a1) + (a2 + a3)) * er[code];
      ri[t] = code;
    }
    __syncthreads();
    for (int off = 64; off > 0; off >>= 1) {
      if (t < off) {
        if (rv[t + off] > rv[t] || (rv[t + off] == rv[t] && ri[t + off] < ri[t])) {
          rv[t] = rv[t + off]; ri[t] = ri[t + off];
        }
      }
      __syncthreads();
    }
    if (t == 0) { rval[fid * MAXTILE + jj] = rv[0]; ridx[fid * MAXTILE + jj] = ri[0]; }
    __syncthreads();
  }
}

// ---------- merge refine results -> final index for flagged rows ----------
__global__ __launch_bounds__(256) void k_merge(const int* __restrict__ cnt,
                                               const int* __restrict__ frow,
                                               const int* __restrict__ nft,
                                               const float* __restrict__ rval,
                                               const int* __restrict__ ridx,
                                               int* __restrict__ idxs,
                                               float* __restrict__ out3) {
  int fid = blockIdx.x * 256 + threadIdx.x;
  int m = cnt[0]; if (m > MAXFLAG) m = MAXFLAG;
  if (fid >= m) return;
  int n = nft[fid];
  float bv = rval[fid * MAXTILE]; int bi = ridx[fid * MAXTILE];
  for (int jj = 1; jj < n; jj++) {
    float v = rval[fid * MAXTILE + jj]; int ix = ridx[fid * MAXTILE + jj];
    if (v > bv || (v == bv && ix < bi)) { bv = v; bi = ix; }
  }
  int row = frow[fid];
  idxs[row] = bi;
  out3[row] = (float)bi;
}

// ---------- counts from final indices (32768 int atomics) ----------
__global__ __launch_bounds__(256) void k_count(const int* __restrict__ idxs,
                                               int* __restrict__ counts) {
  int row = blockIdx.x * 256 + threadIdx.x;
  atomicAdd(&counts[idxs[row]], 1);
}

// ---------- exclusive prefix sum of counts -> offs, curs ----------
__global__ __launch_bounds__(256) void k_prefix(const int* __restrict__ counts,
                                                int* __restrict__ offs,
                                                int* __restrict__ curs) {
  __shared__ int ls[256];
  int t = threadIdx.x;
  int base = t * 32;
  int local[32];
  int s = 0;
  #pragma unroll
  for (int i = 0; i < 32; i++) { local[i] = s; s += counts[base + i]; }
  ls[t] = s;
  __syncthreads();
  for (int off = 1; off < 256; off <<= 1) {
    int add = (t >= off) ? ls[t - off] : 0;
    __syncthreads();
    ls[t] += add;
    __syncthreads();
  }
  int pre = (t == 0) ? 0 : ls[t - 1];
  #pragma unroll
  for (int i = 0; i < 32; i++) {
    int o = pre + local[i];
    offs[base + i] = o;
    curs[base + i] = o;
  }
  if (t == 255) offs[NCODE] = pre + s;
}

// ---------- scatter row ids into per-code buckets ----------
__global__ __launch_bounds__(256) void k_bucket(const int* __restrict__ idxs,
                                                int* __restrict__ curs,
                                                int* __restrict__ bucket) {
  int row = blockIdx.x * 256 + threadIdx.x;
  int idx = idxs[row];
  int pos = atomicAdd(&curs[idx], 1);
  bucket[pos] = row;
}

// ---------- cluster-size EMA + partial sums ----------
__global__ __launch_bounds__(256) void k_cluster(const float* __restrict__ cs,
                                                 const int* __restrict__ counts,
                                                 float* __restrict__ out6,
                                                 double* __restrict__ scal) {
  __shared__ double s1[256], s2[256];
  int t = threadIdx.x;
  int i = blockIdx.x * 256 + t;
  float cf = (float)counts[i];
  float ncs = DECAYF * cs[i] + OMDF * cf;
  out6[i] = ncs;
  s1[t] = (double)ncs;
  s2[t] = (double)cf;
  __syncthreads();
  for (int off = 128; off > 0; off >>= 1) {
    if (t < off) { s1[t] += s1[t + off]; s2[t] += s2[t + off]; }
    __syncthreads();
  }
  if (t == 0) { atomAddD(&scal[0], s1[0]); atomAddD(&scal[1], s2[0]); }
}

// ---------- embedding: bucket-sum + EMA + renormalize (no atomics) ----------
__global__ __launch_bounds__(128) void k_embed(const float* __restrict__ z,
                                               const float* __restrict__ ea,
                                               const int* __restrict__ offs,
                                               const int* __restrict__ bucket,
                                               const float* __restrict__ out6,
                                               const double* __restrict__ scal,
                                               float* __restrict__ out5,
                                               float* __restrict__ out7) {
  __shared__ float red[128];
  int k = blockIdx.x;
  int t = threadIdx.x;
  int beg = offs[k], end = offs[k + 1];
  float s0 = 0.f, s1 = 0.f, s2 = 0.f, s3 = 0.f;
  for (int j = beg; j < end; j++) {
    int r = bucket[j];
    float4 zv = *(const float4*)(z + (size_t)r * 512 + t * 4);
    s0 += zv.x; s1 += zv.y; s2 += zv.z; s3 += zv.w;
  }
  float n = (float)scal[0];
  float ncs = out6[k];
  float csn = (ncs + EPSF) / (n + (float)NCODE * EPSF) * n;
  size_t base = (size_t)k * 512 + t * 4;
  float4 eav = *(const float4*)(ea + base);
  float v[4];
  v[0] = (DECAYF * eav.x + OMDF * s0) / csn;
  v[1] = (DECAYF * eav.y + OMDF * s1) / csn;
  v[2] = (DECAYF * eav.z + OMDF * s2) / csn;
  v[3] = (DECAYF * eav.w + OMDF * s3) / csn;
  float ss = v[0]*v[0] + v[1]*v[1] + v[2]*v[2] + v[3]*v[3];
  red[t] = ss;
  __syncthreads();
  for (int off = 64; off > 0; off >>= 1) {
    if (t < off) red[t] += red[t + off];
    __syncthreads();
  }
  float inv = 1.0f / (sqrtf(red[0]) + EPSF);
  #pragma unroll
  for (int j = 0; j < 4; j++) {
    float nm = v[j] * inv;
    out5[base + j] = nm;
    out7[base + j] = nm * csn;
  }
}

// ---------- gather z_q -> out0 + MSE partials (no atomics) ----------
__global__ __launch_bounds__(256) void k_gather(
    const float* __restrict__ z, const float* __restrict__ emb,
    const int* __restrict__ idxs, float* __restrict__ out0,
    double* __restrict__ loss_part) {
  __shared__ float red[256];
  int t = threadIdx.x;
  int row = blockIdx.x * 8 + (t >> 5);
  int l = t & 31;
  int d0 = l * 16;
  int idx = idxs[row];
  const float4* zp = (const float4*)(z + (size_t)row * 512 + d0);
  const float4* ep = (const float4*)(emb + (size_t)idx * 512 + d0);
  float4* op = (float4*)(out0 + (size_t)row * 512 + d0);
  float ls = 0.f;
  #pragma unroll
  for (int q = 0; q < 4; q++) {
    float4 zv = zp[q];
    float4 ev = ep[q];
    op[q] = ev;  // z + (z_q - z) == z_q
    float dx = zv.x - ev.x, dy = zv.y - ev.y, dz = zv.z - ev.z, dw = zv.w - ev.w;
    ls += dx*dx + dy*dy + dz*dz + dw*dw;
  }
  red[t] = ls;
  __syncthreads();
  for (int off = 128; off > 0; off >>= 1) {
    if (t < off) red[t] += red[t + off];
    __syncthreads();
  }
  if (t == 0) loss_part[blockIdx.x] = (double)red[0];
}

// ---------- scalars ----------
__global__ __launch_bounds__(256) void k_scalars(const int* __restrict__ counts,
                                                 const double* __restrict__ scal,
                                                 const double* __restrict__ loss_part,
                                                 float* __restrict__ out1,
                                                 float* __restrict__ out2,
                                                 float* __restrict__ out4) {
  __shared__ double r1[256], r2[256], r3[256];
  int t = threadIdx.x;
  double csum = scal[1];
  double e1 = 0.0, e2 = 0.0, lsum = 0.0;
  for (int i = t; i < NCODE; i += 256) {
    double c = (double)counts[i];
    double p = c / csum;
    e1 += p * log(p + 1e-10);
    double a = c / (double)BATCH;
    e2 += a * log(a + 1e-10);
  }
  for (int i = t; i < NLOSSBLK; i += 256) lsum += loss_part[i];
  r1[t] = e1; r2[t] = e2; r3[t] = lsum;
  __syncthreads();
  for (int off = 128; off > 0; off >>= 1) {
    if (t < off) { r1[t] += r1[t+off]; r2[t] += r2[t+off]; r3[t] += r3[t+off]; }
    __syncthreads();
  }
  if (t == 0) {
    double entropy = -r1[0];
    double maxent = log((double)NCODE);
    double div = (maxent - entropy) / maxent;
    double mse = r3[0] / ((double)BATCH * (double)DIM);
    double vq = 0.3 * mse + mse + 0.001 * div;
    double perp = exp(-r2[0]);
    *out1 = (float)vq;
    *out2 = (float)perp;
    *out4 = (float)div;
  }
}

extern "C" void kernel_launch(void* const* d_in, const int* in_sizes, int n_in,
                              void* d_out, int out_size, void* d_ws, size_t ws_size,
                              hipStream_t stream) {
  const float* z   = (const float*)d_in[0];
  const float* emb = (const float*)d_in[1];
  const float* cs  = (const float*)d_in[2];
  const float* ea  = (const float*)d_in[3];

  float* out  = (float*)d_out;
  float* out0 = out;                    // z_q_st        [B*D]
  float* out1 = out + 16777216;         // vq_loss       [1]
  float* out2 = out + 16777217;         // perplexity    [1]
  float* out3 = out + 16777218;         // indices       [B]
  float* out4 = out + 16809986;         // diversity     [1]
  float* out5 = out + 16809987;         // new_embedding [K*D]
  float* out6 = out + 21004291;         // new_cluster   [K]
  float* out7 = out + 21012483;         // final_embed_avg [K*D]

  char* ws = (char*)d_ws;
  double* scal      = (double*)(ws + OFF_SCAL);
  int*    cnt       = (int*)   (ws + OFF_CNT);
  int*    counts    = (int*)   (ws + OFF_COUNTS);
  float*  er        = (float*) (ws + OFF_ER);
  int*    idxs      = (int*)   (ws + OFF_IDX);
  double* loss_part = (double*)(ws + OFF_LOSS);
  int*    frow      = (int*)   (ws + OFF_FROW);
  int*    nft       = (int*)   (ws + OFF_NFT);
  int*    ftile     = (int*)   (ws + OFF_FTILE);
  float*  rval      = (float*) (ws + OFF_RVAL);
  int*    ridx      = (int*)   (ws + OFF_RIDX);
  _Float16* eh      = (_Float16*)(ws + OFF_EH);

  // overlays:
  //  zh (fp16 z) on out5/out7 (dead until k_embed writes them)
  //  coarse candidates c1v/c2v/c1i on out0[0 .. 6291456)
  //  bucket structures on out0 tail [13500000 ..) — k_gather (which rewrites
  //  out0) runs after k_embed has consumed them
  _Float16* zh5 = (_Float16*)out5;
  _Float16* zh7 = (_Float16*)out7;
  float* c1v = out0;
  float* c2v = out0 + (size_t)64 * BATCH;
  int*   c1i = (int*)(out0 + (size_t)128 * BATCH);
  int*   offs   = (int*)(out0 + 13500000);   // [NCODE+1]
  int*   curs   = offs + NCODE + 64;         // [NCODE]
  int*   bucket = curs + NCODE;              // [BATCH]

  hipMemsetAsync(ws, 0, OFF_ER, stream);  // scal, cnt, counts

  k_prep_e<<<NCODE / 4, 256, 0, stream>>>(emb, er, eh);
  k_prep_z<<<8192, 256, 0, stream>>>(z, zh5, zh7);
  k_coarse<<<dim3(BATCH / 128, NCODE / 128), 256, 0, stream>>>(eh, zh5, zh7, c1v, c2v, c1i);
  k_combine<<<BATCH / 256, 256, 0, stream>>>(c1v, c2v, c1i, idxs, out3, cnt, frow, nft, ftile);
  k_refine<<<MAXFLAG, 256, 0, stream>>>(z, emb, er, cnt, frow, nft, ftile, rval, ridx);
  k_merge<<<MAXFLAG / 256, 256, 0, stream>>>(cnt, frow, nft, rval, ridx, idxs, out3);

  k_count<<<BATCH / 256, 256, 0, stream>>>(idxs, counts);
  k_cluster<<<NCODE / 256, 256, 0, stream>>>(cs, counts, out6, scal);
  k_prefix<<<1, 256, 0, stream>>>(counts, offs, curs);
  k_bucket<<<BATCH / 256, 256, 0, stream>>>(idxs, curs, bucket);
  k_embed<<<NCODE, 128, 0, stream>>>(z, ea, offs, bucket, out6, scal, out5, out7);

  k_gather<<<NLOSSBLK, 256, 0, stream>>>(z, emb, idxs, out0, loss_part);
  k_scalars<<<1, 256, 0, stream>>>(counts, scal, loss_part, out1, out2, out4);
}

// Round 5
// 853.402 us; speedup vs baseline: 1.5852x; 1.5852x over previous
//
#include <hip/hip_runtime.h>
#include <math.h>

#define BATCH 32768
#define DIM   512
#define NCODE 8192
#define DECAYF 0.995f
#define OMDF   0.005f
#define EPSF   1e-8f
#define MARGIN 8e-3f
#define MAXFLAG 2048
#define MAXTILE 12

typedef _Float16 half8 __attribute__((ext_vector_type(8)));
typedef _Float16 half4 __attribute__((ext_vector_type(4)));
typedef float f32x4 __attribute__((ext_vector_type(4)));

// ---------------- workspace layout (bytes) ----------------
#define OFF_SCAL   0        // double scal[8]: [0]=n_sum [1]=counts_sum
#define OFF_CNT    64       // int cnt
#define OFF_COUNTS 128      // int counts[NCODE]
#define OFF_ER     32896    // float er[NCODE]
#define OFF_IDX    65664    // int idxs[BATCH]
#define OFF_LOSS   196736   // double loss_part[4096]
#define OFF_FROW   229504   // int frow[MAXFLAG]
#define OFF_NFT    237696   // int nft[MAXFLAG]
#define OFF_FTILE  245888   // int ftile[MAXFLAG*MAXTILE]
#define OFF_RVAL   344192   // float rval[MAXFLAG*MAXTILE]
#define OFF_RIDX   442496   // int ridx[MAXFLAG*MAXTILE]
#define OFF_EH     540800   // _Float16 eh[NCODE*DIM]  (8 MB)
#define NLOSSBLK   4096

__device__ inline void atomAddD(double* p, double v){ unsafeAtomicAdd(p, v); }

__device__ inline void async_cp16(const _Float16* g, _Float16* l) {
  __builtin_amdgcn_global_load_lds(
      (const __attribute__((address_space(1))) unsigned int*)g,
      (__attribute__((address_space(3))) unsigned int*)l, 16, 0, 0);
}

// ---------- prep: er[k]=1/(||e_k||+eps), eh = fp16(e*er) ----------
__global__ __launch_bounds__(256) void k_prep_e(const float* __restrict__ emb,
                                                float* __restrict__ er,
                                                _Float16* __restrict__ eh) {
  int row = blockIdx.x * 4 + (threadIdx.x >> 6);
  int l = threadIdx.x & 63;
  const float4* p = (const float4*)(emb + (size_t)row * DIM);
  float4 a = p[l], b = p[l + 64];
  float s = a.x*a.x + a.y*a.y + a.z*a.z + a.w*a.w
          + b.x*b.x + b.y*b.y + b.z*b.z + b.w*b.w;
  #pragma unroll
  for (int off = 32; off > 0; off >>= 1) s += __shfl_down(s, off);
  s = __shfl(s, 0);
  float inv = 1.0f / (sqrtf(s) + EPSF);
  if (l == 0) er[row] = inv;
  half4 ha = { (_Float16)(a.x*inv), (_Float16)(a.y*inv), (_Float16)(a.z*inv), (_Float16)(a.w*inv) };
  half4 hb = { (_Float16)(b.x*inv), (_Float16)(b.y*inv), (_Float16)(b.z*inv), (_Float16)(b.w*inv) };
  *(half4*)(eh + (size_t)row * DIM + l * 4) = ha;
  *(half4*)(eh + (size_t)row * DIM + 256 + l * 4) = hb;
}

// ---------- prep: zh = fp16(z) split across out5/out7 regions ----------
__global__ __launch_bounds__(256) void k_prep_z(const float* __restrict__ z,
                                                _Float16* __restrict__ z5,
                                                _Float16* __restrict__ z7) {
  size_t base = ((size_t)blockIdx.x * 256 + threadIdx.x) * 8;
  const float4* zp = (const float4*)(z + base);
  float4 a = zp[0], b = zp[1];
  half8 h = { (_Float16)a.x, (_Float16)a.y, (_Float16)a.z, (_Float16)a.w,
              (_Float16)b.x, (_Float16)b.y, (_Float16)b.z, (_Float16)b.w };
  _Float16* dst = (base < (size_t)16384 * 512) ? (z5 + base)
                                               : (z7 + (base - (size_t)16384 * 512));
  *(half8*)dst = h;
}

// ---------- coarse fp16 MFMA GEMM + per-row top-2 per 128-col tile ----------
// Double-buffered 2-phase pipeline with STATIC buffer identities: As0/As1 and
// Bs0/Bs1 are distinct __shared__ objects, so the compiler's alias analysis
// can prove that the next tile's global_load_lds (into buffer 1) does not
// alias the current tile's ds_reads (from buffer 0) and leaves the prefetch
// in flight across the MFMAs.  (With a single runtime-indexed As[2][...] the
// compiler inserted a conservative vmcnt(0) wait before the reads — measured
// regression in round 3.)  One __syncthreads per K-step; fragment values and
// accumulation order are bit-identical to the verified round-0 kernel.
__global__ __launch_bounds__(256) void k_coarse(const _Float16* __restrict__ eh,
                                                const _Float16* __restrict__ z5,
                                                const _Float16* __restrict__ z7,
                                                float* __restrict__ c1v,
                                                float* __restrict__ c2v,
                                                int* __restrict__ c1i) {
  __shared__ _Float16 As0[4096];  // 128 rows x 32 k (swizzled)
  __shared__ _Float16 As1[4096];
  __shared__ _Float16 Bs0[4096];  // 128 codes x 32 k (swizzled)
  __shared__ _Float16 Bs1[4096];
  __shared__ float ev1[2][128];
  __shared__ float ev2[2][128];
  __shared__ int   ei1[2][128];

  const int t = threadIdx.x, w = t >> 6, lane = t & 63;
  const int quad = lane >> 4, c16 = lane & 15;
  const int row0 = blockIdx.x * 128;
  const int by = blockIdx.y, col0 = by * 128;
  const int m0 = (w & 1) * 64, n0 = (w >> 1) * 64;
  const _Float16* zbase = (row0 < 16384) ? z5 : (z7 - (size_t)16384 * 512);

  const int kq = (lane & 3) ^ ((lane >> 3) & 3);   // swizzled k-quad this lane fetches
  const _Float16* ga[2]; const _Float16* gb[2];
  int lo[2];
  #pragma unroll
  for (int c = 0; c < 2; c++) {
    int r = (c * 4 + w) * 16 + (lane >> 2);
    ga[c] = zbase + (size_t)(row0 + r) * 512 + kq * 8;
    gb[c] = eh + (size_t)(col0 + r) * 512 + kq * 8;
    lo[c] = (c * 4 + w) * 512;
  }

  f32x4 acc[4][4];
  #pragma unroll
  for (int i = 0; i < 4; i++)
    #pragma unroll
    for (int j = 0; j < 4; j++) { acc[i][j][0]=0.f; acc[i][j][1]=0.f; acc[i][j][2]=0.f; acc[i][j][3]=0.f; }

  // fragment read offsets (halfs): group g = (m0>>4)+i, slot = c16*4 + (quad ^ ((c16>>1)&3))
  const int sw = (c16 * 4 + (quad ^ ((c16 >> 1) & 3))) * 8;
  int offA[4], offB[4];
  #pragma unroll
  for (int i = 0; i < 4; i++) offA[i] = ((m0 >> 4) + i) * 512 + sw;
  #pragma unroll
  for (int j = 0; j < 4; j++) offB[j] = ((n0 >> 4) + j) * 512 + sw;

#define STAGE_TO(Abuf, Bbuf) do {                                   \
    _Pragma("unroll")                                               \
    for (int c_ = 0; c_ < 2; c_++) {                                \
      async_cp16(ga[c_], (Abuf) + lo[c_]); ga[c_] += 32;            \
      async_cp16(gb[c_], (Bbuf) + lo[c_]); gb[c_] += 32;            \
    }                                                               \
  } while (0)

#define COMPUTE_FROM(Abuf, Bbuf) do {                               \
    half8 af[4], bf[4];                                             \
    _Pragma("unroll")                                               \
    for (int i_ = 0; i_ < 4; i_++) af[i_] = *(const half8*)((Abuf) + offA[i_]); \
    _Pragma("unroll")                                               \
    for (int j_ = 0; j_ < 4; j_++) bf[j_] = *(const half8*)((Bbuf) + offB[j_]); \
    _Pragma("unroll")                                               \
    for (int i_ = 0; i_ < 4; i_++)                                  \
      _Pragma("unroll")                                             \
      for (int j_ = 0; j_ < 4; j_++)                                \
        acc[i_][j_] = __builtin_amdgcn_mfma_f32_16x16x32_f16(af[i_], bf[j_], acc[i_][j_], 0, 0, 0); \
  } while (0)

  // prologue: stage tile 0 into buffer 0
  STAGE_TO(As0, Bs0);
  __syncthreads();

  #pragma unroll
  for (int kk = 0; kk < 16; kk += 2) {
    if (kk + 1 < 16) STAGE_TO(As1, Bs1);    // prefetch tile kk+1
    COMPUTE_FROM(As0, Bs0);                 // compute tile kk
    __syncthreads();
    if (kk + 2 < 16) STAGE_TO(As0, Bs0);    // prefetch tile kk+2
    COMPUTE_FROM(As1, Bs1);                 // compute tile kk+1
    __syncthreads();
  }
#undef STAGE_TO
#undef COMPUTE_FROM

  // epilogue: per-row top-2 over this block's 128 cols
  const int h = w >> 1;
  #pragma unroll
  for (int i = 0; i < 4; i++) {
    #pragma unroll
    for (int r = 0; r < 4; r++) {
      float v1 = acc[i][0][r];
      int   i1 = col0 + n0 + c16;
      float v2 = -3.0e38f;
      #pragma unroll
      for (int j = 1; j < 4; j++) {
        float v = acc[i][j][r];
        int ix = col0 + n0 + j * 16 + c16;
        if (v > v1) { v2 = fmaxf(v2, v1); v1 = v; i1 = ix; }
        else        { v2 = fmaxf(v2, v); }
      }
      #pragma unroll
      for (int m = 1; m < 16; m <<= 1) {
        float o1 = __shfl_xor(v1, m);
        float o2 = __shfl_xor(v2, m);
        int   oi = __shfl_xor(i1, m);
        if (o1 > v1 || (o1 == v1 && oi < i1)) { v2 = fmaxf(v1, o2); v1 = o1; i1 = oi; }
        else                                  { v2 = fmaxf(v2, o1); }
      }
      if (c16 == 0) {
        int rl = (w & 1) * 64 + i * 16 + quad * 4 + r;
        ev1[h][rl] = v1; ev2[h][rl] = v2; ei1[h][rl] = i1;
      }
    }
  }
  __syncthreads();
  if (t < 128) {
    float a1 = ev1[0][t], a2 = ev2[0][t]; int ai = ei1[0][t];
    float b1 = ev1[1][t], b2 = ev2[1][t]; int bi = ei1[1][t];
    float v1, v2; int i1;
    if (b1 > a1 || (b1 == a1 && bi < ai)) { v1 = b1; i1 = bi; v2 = fmaxf(a1, b2); }
    else                                  { v1 = a1; i1 = ai; v2 = fmaxf(a2, b1); }
    size_t o = (size_t)by * BATCH + row0 + t;
    c1v[o] = v1; c2v[o] = v2; c1i[o] = i1;
  }
}

// ---------- combine 64 tiles/row, margin test, flag list ----------
__global__ __launch_bounds__(256) void k_combine(const float* __restrict__ c1v,
                                                 const float* __restrict__ c2v,
                                                 const int* __restrict__ c1i,
                                                 int* __restrict__ idxs,
                                                 float* __restrict__ out3,
                                                 int* __restrict__ cnt,
                                                 int* __restrict__ frow,
                                                 int* __restrict__ nft,
                                                 int* __restrict__ ftile) {
  int row = blockIdx.x * 256 + threadIdx.x;
  float v1 = -3.0e38f, v2 = -3.0e38f; int i1 = 0;
  for (int ti = 0; ti < 64; ti++) {
    size_t o = (size_t)ti * BATCH + row;
    float a = c1v[o]; float a2 = c2v[o]; int ai = c1i[o];
    if (a > v1 || (a == v1 && ai < i1)) { v2 = fmaxf(v1, a2); v1 = a; i1 = ai; }
    else                                { v2 = fmaxf(v2, a); }
  }
  idxs[row] = i1;
  out3[row] = (float)i1;
  if (v1 - v2 < MARGIN) {
    int fid = atomicAdd(cnt, 1);
    if (fid < MAXFLAG) {
      frow[fid] = row;
      int jj = 0;
      for (int ti = 0; ti < 64; ti++) {
        if (c1v[(size_t)ti * BATCH + row] >= v1 - MARGIN && jj < MAXTILE)
          ftile[fid * MAXTILE + jj++] = ti;
      }
      nft[fid] = jj;
    }
  }
}

// ---------- exact fp32 refine of qualifying tiles for flagged rows ----------
__global__ __launch_bounds__(256) void k_refine(const float* __restrict__ z,
                                                const float* __restrict__ emb,
                                                const float* __restrict__ er,
                                                const int* __restrict__ cnt,
                                                const int* __restrict__ frow,
                                                const int* __restrict__ nft,
                                                const int* __restrict__ ftile,
                                                float* __restrict__ rval,
                                                int* __restrict__ ridx) {
  __shared__ float zl[512];
  __shared__ float rv[128];
  __shared__ int   ri[128];
  int fid = blockIdx.x;
  int m = cnt[0]; if (m > MAXFLAG) m = MAXFLAG;
  if (fid >= m) return;
  int t = threadIdx.x;
  int row = frow[fid];
  if (t < 128) ((float4*)zl)[t] = *(const float4*)(z + (size_t)row * 512 + t * 4);
  __syncthreads();
  int n = nft[fid];
  for (int jj = 0; jj < n; jj++) {
    int ti = ftile[fid * MAXTILE + jj];
    if (t < 128) {
      int code = ti * 128 + t;
      const float4* ep = (const float4*)(emb + (size_t)code * 512);
      const float4* zp = (const float4*)zl;
      float a0 = 0.f, a1 = 0.f, a2 = 0.f, a3 = 0.f;
      #pragma unroll 8
      for (int d = 0; d < 128; d++) {
        float4 e4 = ep[d]; float4 z4 = zp[d];
        a0 = fmaf(e4.x, z4.x, a0); a1 = fmaf(e4.y, z4.y, a1);
        a2 = fmaf(e4.z, z4.z, a2); a3 = fmaf(e4.w, z4.w, a3);
      }
      rv[t] = ((a0 + a1) + (a2 + a3)) * er[code];
      ri[t] = code;
    }
    __syncthreads();
    for (int off = 64; off > 0; off >>= 1) {
      if (t < off) {
        if (rv[t + off] > rv[t] || (rv[t + off] == rv[t] && ri[t + off] < ri[t])) {
          rv[t] = rv[t + off]; ri[t] = ri[t + off];
        }
      }
      __syncthreads();
    }
    if (t == 0) { rval[fid * MAXTILE + jj] = rv[0]; ridx[fid * MAXTILE + jj] = ri[0]; }
    __syncthreads();
  }
}

// ---------- merge refine results -> final index for flagged rows ----------
__global__ __launch_bounds__(256) void k_merge(const int* __restrict__ cnt,
                                               const int* __restrict__ frow,
                                               const int* __restrict__ nft,
                                               const float* __restrict__ rval,
                                               const int* __restrict__ ridx,
                                               int* __restrict__ idxs,
                                               float* __restrict__ out3) {
  int fid = blockIdx.x * 256 + threadIdx.x;
  int m = cnt[0]; if (m > MAXFLAG) m = MAXFLAG;
  if (fid >= m) return;
  int n = nft[fid];
  float bv = rval[fid * MAXTILE]; int bi = ridx[fid * MAXTILE];
  for (int jj = 1; jj < n; jj++) {
    float v = rval[fid * MAXTILE + jj]; int ix = ridx[fid * MAXTILE + jj];
    if (v > bv || (v == bv && ix < bi)) { bv = v; bi = ix; }
  }
  int row = frow[fid];
  idxs[row] = bi;
  out3[row] = (float)bi;
}

// ---------- counts from final indices (32768 int atomics) ----------
__global__ __launch_bounds__(256) void k_count(const int* __restrict__ idxs,
                                               int* __restrict__ counts) {
  int row = blockIdx.x * 256 + threadIdx.x;
  atomicAdd(&counts[idxs[row]], 1);
}

// ---------- exclusive prefix sum of counts -> offs, curs ----------
__global__ __launch_bounds__(256) void k_prefix(const int* __restrict__ counts,
                                                int* __restrict__ offs,
                                                int* __restrict__ curs) {
  __shared__ int ls[256];
  int t = threadIdx.x;
  int base = t * 32;
  int local[32];
  int s = 0;
  #pragma unroll
  for (int i = 0; i < 32; i++) { local[i] = s; s += counts[base + i]; }
  ls[t] = s;
  __syncthreads();
  for (int off = 1; off < 256; off <<= 1) {
    int add = (t >= off) ? ls[t - off] : 0;
    __syncthreads();
    ls[t] += add;
    __syncthreads();
  }
  int pre = (t == 0) ? 0 : ls[t - 1];
  #pragma unroll
  for (int i = 0; i < 32; i++) {
    int o = pre + local[i];
    offs[base + i] = o;
    curs[base + i] = o;
  }
  if (t == 255) offs[NCODE] = pre + s;
}

// ---------- scatter row ids into per-code buckets ----------
__global__ __launch_bounds__(256) void k_bucket(const int* __restrict__ idxs,
                                                int* __restrict__ curs,
                                                int* __restrict__ bucket) {
  int row = blockIdx.x * 256 + threadIdx.x;
  int idx = idxs[row];
  int pos = atomicAdd(&curs[idx], 1);
  bucket[pos] = row;
}

// ---------- cluster-size EMA + partial sums ----------
__global__ __launch_bounds__(256) void k_cluster(const float* __restrict__ cs,
                                                 const int* __restrict__ counts,
                                                 float* __restrict__ out6,
                                                 double* __restrict__ scal) {
  __shared__ double s1[256], s2[256];
  int t = threadIdx.x;
  int i = blockIdx.x * 256 + t;
  float cf = (float)counts[i];
  float ncs = DECAYF * cs[i] + OMDF * cf;
  out6[i] = ncs;
  s1[t] = (double)ncs;
  s2[t] = (double)cf;
  __syncthreads();
  for (int off = 128; off > 0; off >>= 1) {
    if (t < off) { s1[t] += s1[t + off]; s2[t] += s2[t + off]; }
    __syncthreads();
  }
  if (t == 0) { atomAddD(&scal[0], s1[0]); atomAddD(&scal[1], s2[0]); }
}

// ---------- embedding: bucket-sum + EMA + renormalize (no atomics) ----------
__global__ __launch_bounds__(128) void k_embed(const float* __restrict__ z,
                                               const float* __restrict__ ea,
                                               const int* __restrict__ offs,
                                               const int* __restrict__ bucket,
                                               const float* __restrict__ out6,
                                               const double* __restrict__ scal,
                                               float* __restrict__ out5,
                                               float* __restrict__ out7) {
  __shared__ float red[128];
  int k = blockIdx.x;
  int t = threadIdx.x;
  int beg = offs[k], end = offs[k + 1];
  float s0 = 0.f, s1 = 0.f, s2 = 0.f, s3 = 0.f;
  for (int j = beg; j < end; j++) {
    int r = bucket[j];
    float4 zv = *(const float4*)(z + (size_t)r * 512 + t * 4);
    s0 += zv.x; s1 += zv.y; s2 += zv.z; s3 += zv.w;
  }
  float n = (float)scal[0];
  float ncs = out6[k];
  float csn = (ncs + EPSF) / (n + (float)NCODE * EPSF) * n;
  size_t base = (size_t)k * 512 + t * 4;
  float4 eav = *(const float4*)(ea + base);
  float v[4];
  v[0] = (DECAYF * eav.x + OMDF * s0) / csn;
  v[1] = (DECAYF * eav.y + OMDF * s1) / csn;
  v[2] = (DECAYF * eav.z + OMDF * s2) / csn;
  v[3] = (DECAYF * eav.w + OMDF * s3) / csn;
  float ss = v[0]*v[0] + v[1]*v[1] + v[2]*v[2] + v[3]*v[3];
  red[t] = ss;
  __syncthreads();
  for (int off = 64; off > 0; off >>= 1) {
    if (t < off) red[t] += red[t + off];
    __syncthreads();
  }
  float inv = 1.0f / (sqrtf(red[0]) + EPSF);
  #pragma unroll
  for (int j = 0; j < 4; j++) {
    float nm = v[j] * inv;
    out5[base + j] = nm;
    out7[base + j] = nm * csn;
  }
}

// ---------- gather z_q -> out0 + MSE partials (no atomics) ----------
__global__ __launch_bounds__(256) void k_gather(
    const float* __restrict__ z, const float* __restrict__ emb,
    const int* __restrict__ idxs, float* __restrict__ out0,
    double* __restrict__ loss_part) {
  __shared__ float red[256];
  int t = threadIdx.x;
  int row = blockIdx.x * 8 + (t >> 5);
  int l = t & 31;
  int d0 = l * 16;
  int idx = idxs[row];
  const float4* zp = (const float4*)(z + (size_t)row * 512 + d0);
  const float4* ep = (const float4*)(emb + (size_t)idx * 512 + d0);
  float4* op = (float4*)(out0 + (size_t)row * 512 + d0);
  float ls = 0.f;
  #pragma unroll
  for (int q = 0; q < 4; q++) {
    float4 zv = zp[q];
    float4 ev = ep[q];
    op[q] = ev;  // z + (z_q - z) == z_q
    float dx = zv.x - ev.x, dy = zv.y - ev.y, dz = zv.z - ev.z, dw = zv.w - ev.w;
    ls += dx*dx + dy*dy + dz*dz + dw*dw;
  }
  red[t] = ls;
  __syncthreads();
  for (int off = 128; off > 0; off >>= 1) {
    if (t < off) red[t] += red[t + off];
    __syncthreads();
  }
  if (t == 0) loss_part[blockIdx.x] = (double)red[0];
}

// ---------- scalars ----------
__global__ __launch_bounds__(256) void k_scalars(const int* __restrict__ counts,
                                                 const double* __restrict__ scal,
                                                 const double* __restrict__ loss_part,
                                                 float* __restrict__ out1,
                                                 float* __restrict__ out2,
                                                 float* __restrict__ out4) {
  __shared__ double r1[256], r2[256], r3[256];
  int t = threadIdx.x;
  double csum = scal[1];
  double e1 = 0.0, e2 = 0.0, lsum = 0.0;
  for (int i = t; i < NCODE; i += 256) {
    double c = (double)counts[i];
    double p = c / csum;
    e1 += p * log(p + 1e-10);
    double a = c / (double)BATCH;
    e2 += a * log(a + 1e-10);
  }
  for (int i = t; i < NLOSSBLK; i += 256) lsum += loss_part[i];
  r1[t] = e1; r2[t] = e2; r3[t] = lsum;
  __syncthreads();
  for (int off = 128; off > 0; off >>= 1) {
    if (t < off) { r1[t] += r1[t+off]; r2[t] += r2[t+off]; r3[t] += r3[t+off]; }
    __syncthreads();
  }
  if (t == 0) {
    double entropy = -r1[0];
    double maxent = log((double)NCODE);
    double div = (maxent - entropy) / maxent;
    double mse = r3[0] / ((double)BATCH * (double)DIM);
    double vq = 0.3 * mse + mse + 0.001 * div;
    double perp = exp(-r2[0]);
    *out1 = (float)vq;
    *out2 = (float)perp;
    *out4 = (float)div;
  }
}

extern "C" void kernel_launch(void* const* d_in, const int* in_sizes, int n_in,
                              void* d_out, int out_size, void* d_ws, size_t ws_size,
                              hipStream_t stream) {
  const float* z   = (const float*)d_in[0];
  const float* emb = (const float*)d_in[1];
  const float* cs  = (const float*)d_in[2];
  const float* ea  = (const float*)d_in[3];

  float* out  = (float*)d_out;
  float* out0 = out;                    // z_q_st        [B*D]
  float* out1 = out + 16777216;         // vq_loss       [1]
  float* out2 = out + 16777217;         // perplexity    [1]
  float* out3 = out + 16777218;         // indices       [B]
  float* out4 = out + 16809986;         // diversity     [1]
  float* out5 = out + 16809987;         // new_embedding [K*D]
  float* out6 = out + 21004291;         // new_cluster   [K]
  float* out7 = out + 21012483;         // final_embed_avg [K*D]

  char* ws = (char*)d_ws;
  double* scal      = (double*)(ws + OFF_SCAL);
  int*    cnt       = (int*)   (ws + OFF_CNT);
  int*    counts    = (int*)   (ws + OFF_COUNTS);
  float*  er        = (float*) (ws + OFF_ER);
  int*    idxs      = (int*)   (ws + OFF_IDX);
  double* loss_part = (double*)(ws + OFF_LOSS);
  int*    frow      = (int*)   (ws + OFF_FROW);
  int*    nft       = (int*)   (ws + OFF_NFT);
  int*    ftile     = (int*)   (ws + OFF_FTILE);
  float*  rval      = (float*) (ws + OFF_RVAL);
  int*    ridx      = (int*)   (ws + OFF_RIDX);
  _Float16* eh      = (_Float16*)(ws + OFF_EH);

  // overlays:
  //  zh (fp16 z) on out5/out7 (dead until k_embed writes them)
  //  coarse candidates c1v/c2v/c1i on out0[0 .. 6291456)
  //  bucket structures on out0 tail [13500000 ..) — k_gather (which rewrites
  //  out0) runs after k_embed has consumed them
  _Float16* zh5 = (_Float16*)out5;
  _Float16* zh7 = (_Float16*)out7;
  float* c1v = out0;
  float* c2v = out0 + (size_t)64 * BATCH;
  int*   c1i = (int*)(out0 + (size_t)128 * BATCH);
  int*   offs   = (int*)(out0 + 13500000);   // [NCODE+1]
  int*   curs   = offs + NCODE + 64;         // [NCODE]
  int*   bucket = curs + NCODE;              // [BATCH]

  hipMemsetAsync(ws, 0, OFF_ER, stream);  // scal, cnt, counts

  k_prep_e<<<NCODE / 4, 256, 0, stream>>>(emb, er, eh);
  k_prep_z<<<8192, 256, 0, stream>>>(z, zh5, zh7);
  k_coarse<<<dim3(BATCH / 128, NCODE / 128), 256, 0, stream>>>(eh, zh5, zh7, c1v, c2v, c1i);
  k_combine<<<BATCH / 256, 256, 0, stream>>>(c1v, c2v, c1i, idxs, out3, cnt, frow, nft, ftile);
  k_refine<<<MAXFLAG, 256, 0, stream>>>(z, emb, er, cnt, frow, nft, ftile, rval, ridx);
  k_merge<<<MAXFLAG / 256, 256, 0, stream>>>(cnt, frow, nft, rval, ridx, idxs, out3);

  k_count<<<BATCH / 256, 256, 0, stream>>>(idxs, counts);
  k_cluster<<<NCODE / 256, 256, 0, stream>>>(cs, counts, out6, scal);
  k_prefix<<<1, 256, 0, stream>>>(counts, offs, curs);
  k_bucket<<<BATCH / 256, 256, 0, stream>>>(idxs, curs, bucket);
  k_embed<<<NCODE, 128, 0, stream>>>(z, ea, offs, bucket, out6, scal, out5, out7);

  k_gather<<<NLOSSBLK, 256, 0, stream>>>(z, emb, idxs, out0, loss_part);
  k_scalars<<<1, 256, 0, stream>>>(counts, scal, loss_part, out1, out2, out4);
}

// Round 7
// 798.501 us; speedup vs baseline: 1.6942x; 1.0688x over previous
//
#include <hip/hip_runtime.h>
#include <math.h>

#define BATCH 32768
#define DIM   512
#define NCODE 8192
#define DECAYF 0.995f
#define OMDF   0.005f
#define EPSF   1e-8f
#define MARGIN 8e-3f
#define MAXFLAG 2048
#define MAXTILE 12

typedef _Float16 half8 __attribute__((ext_vector_type(8)));
typedef _Float16 half4 __attribute__((ext_vector_type(4)));
typedef float f32x4 __attribute__((ext_vector_type(4)));

// ---------------- workspace layout (bytes) ----------------
#define OFF_SCAL   0        // double scal[8]: [0]=n_sum [1]=counts_sum
#define OFF_CNT    64       // int cnt
#define OFF_COUNTS 128      // int counts[NCODE]
#define OFF_ER     32896    // float er[NCODE]
#define OFF_IDX    65664    // int idxs[BATCH]
#define OFF_LOSS   196736   // double loss_part[4096]
#define OFF_FROW   229504   // int frow[MAXFLAG]
#define OFF_NFT    237696   // int nft[MAXFLAG]
#define OFF_FTILE  245888   // int ftile[MAXFLAG*MAXTILE]
#define OFF_RVAL   344192   // float rval[MAXFLAG*MAXTILE]
#define OFF_RIDX   442496   // int ridx[MAXFLAG*MAXTILE]
#define OFF_EH     540800   // _Float16 eh[NCODE*DIM]  (8 MB)
#define NLOSSBLK   4096

__device__ inline void atomAddD(double* p, double v){ unsafeAtomicAdd(p, v); }

__device__ inline void async_cp16(const _Float16* g, _Float16* l) {
  __builtin_amdgcn_global_load_lds(
      (const __attribute__((address_space(1))) unsigned int*)g,
      (__attribute__((address_space(3))) unsigned int*)l, 16, 0, 0);
}

// DPP row_ror lane rotation within 16-lane rows (VALU pipe, not DS).
// row_ror:N ctrl = 0x120+N.
template<int CTRL>
__device__ inline float dpp_rotf(float v) {
  return __int_as_float(__builtin_amdgcn_mov_dpp(__float_as_int(v), CTRL, 0xF, 0xF, false));
}
template<int CTRL>
__device__ inline int dpp_roti(int v) {
  return __builtin_amdgcn_mov_dpp(v, CTRL, 0xF, 0xF, false);
}

// ---------- prep: er[k]=1/(||e_k||+eps), eh = fp16(e*er) ----------
__global__ __launch_bounds__(256) void k_prep_e(const float* __restrict__ emb,
                                                float* __restrict__ er,
                                                _Float16* __restrict__ eh) {
  int row = blockIdx.x * 4 + (threadIdx.x >> 6);
  int l = threadIdx.x & 63;
  const float4* p = (const float4*)(emb + (size_t)row * DIM);
  float4 a = p[l], b = p[l + 64];
  float s = a.x*a.x + a.y*a.y + a.z*a.z + a.w*a.w
          + b.x*b.x + b.y*b.y + b.z*b.z + b.w*b.w;
  #pragma unroll
  for (int off = 32; off > 0; off >>= 1) s += __shfl_down(s, off);
  s = __shfl(s, 0);
  float inv = 1.0f / (sqrtf(s) + EPSF);
  if (l == 0) er[row] = inv;
  half4 ha = { (_Float16)(a.x*inv), (_Float16)(a.y*inv), (_Float16)(a.z*inv), (_Float16)(a.w*inv) };
  half4 hb = { (_Float16)(b.x*inv), (_Float16)(b.y*inv), (_Float16)(b.z*inv), (_Float16)(b.w*inv) };
  *(half4*)(eh + (size_t)row * DIM + l * 4) = ha;
  *(half4*)(eh + (size_t)row * DIM + 256 + l * 4) = hb;
}

// ---------- prep: zh = fp16(z) split across out5/out7 regions ----------
__global__ __launch_bounds__(256) void k_prep_z(const float* __restrict__ z,
                                                _Float16* __restrict__ z5,
                                                _Float16* __restrict__ z7) {
  size_t base = ((size_t)blockIdx.x * 256 + threadIdx.x) * 8;
  const float4* zp = (const float4*)(z + base);
  float4 a = zp[0], b = zp[1];
  half8 h = { (_Float16)a.x, (_Float16)a.y, (_Float16)a.z, (_Float16)a.w,
              (_Float16)b.x, (_Float16)b.y, (_Float16)b.z, (_Float16)b.w };
  _Float16* dst = (base < (size_t)16384 * 512) ? (z5 + base)
                                               : (z7 + (base - (size_t)16384 * 512));
  *(half8*)dst = h;
}

// ---------- coarse fp16 MFMA GEMM + per-row top-2 per 128-col tile ----------
// Double-buffered 2-phase pipeline with STATIC buffer identities (round-5
// verified: compiler alias analysis keeps the prefetch in flight).  Epilogue
// top-2 reduction uses DPP row_ror rotations (VALU pipe) instead of
// __shfl_xor (ds_bpermute, DS pipe): the DS pipe was ~65% subscribed and the
// 192 bpermutes/lane of the old butterfly exceeded the K-loop's 128 ds_reads.
// Top-2 merge is an exact associative+commutative set function and rotation
// coverage sets are disjoint per step, so results are bit-identical.
__global__ __launch_bounds__(256) void k_coarse(const _Float16* __restrict__ eh,
                                                const _Float16* __restrict__ z5,
                                                const _Float16* __restrict__ z7,
                                                float* __restrict__ c1v,
                                                float* __restrict__ c2v,
                                                int* __restrict__ c1i) {
  __shared__ _Float16 As0[4096];  // 128 rows x 32 k (swizzled)
  __shared__ _Float16 As1[4096];
  __shared__ _Float16 Bs0[4096];  // 128 codes x 32 k (swizzled)
  __shared__ _Float16 Bs1[4096];
  __shared__ float ev1[2][128];
  __shared__ float ev2[2][128];
  __shared__ int   ei1[2][128];

  const int t = threadIdx.x, w = t >> 6, lane = t & 63;
  const int quad = lane >> 4, c16 = lane & 15;
  const int row0 = blockIdx.x * 128;
  const int by = blockIdx.y, col0 = by * 128;
  const int m0 = (w & 1) * 64, n0 = (w >> 1) * 64;
  const _Float16* zbase = (row0 < 16384) ? z5 : (z7 - (size_t)16384 * 512);

  const int kq = (lane & 3) ^ ((lane >> 3) & 3);   // swizzled k-quad this lane fetches
  const _Float16* ga[2]; const _Float16* gb[2];
  int lo[2];
  #pragma unroll
  for (int c = 0; c < 2; c++) {
    int r = (c * 4 + w) * 16 + (lane >> 2);
    ga[c] = zbase + (size_t)(row0 + r) * 512 + kq * 8;
    gb[c] = eh + (size_t)(col0 + r) * 512 + kq * 8;
    lo[c] = (c * 4 + w) * 512;
  }

  f32x4 acc[4][4];
  #pragma unroll
  for (int i = 0; i < 4; i++)
    #pragma unroll
    for (int j = 0; j < 4; j++) { acc[i][j][0]=0.f; acc[i][j][1]=0.f; acc[i][j][2]=0.f; acc[i][j][3]=0.f; }

  // fragment read offsets (halfs): group g = (m0>>4)+i, slot = c16*4 + (quad ^ ((c16>>1)&3))
  const int sw = (c16 * 4 + (quad ^ ((c16 >> 1) & 3))) * 8;
  int offA[4], offB[4];
  #pragma unroll
  for (int i = 0; i < 4; i++) offA[i] = ((m0 >> 4) + i) * 512 + sw;
  #pragma unroll
  for (int j = 0; j < 4; j++) offB[j] = ((n0 >> 4) + j) * 512 + sw;

#define STAGE_TO(Abuf, Bbuf) do {                                   \
    _Pragma("unroll")                                               \
    for (int c_ = 0; c_ < 2; c_++) {                                \
      async_cp16(ga[c_], (Abuf) + lo[c_]); ga[c_] += 32;            \
      async_cp16(gb[c_], (Bbuf) + lo[c_]); gb[c_] += 32;            \
    }                                                               \
  } while (0)

#define COMPUTE_FROM(Abuf, Bbuf) do {                               \
    half8 af[4], bf[4];                                             \
    _Pragma("unroll")                                               \
    for (int i_ = 0; i_ < 4; i_++) af[i_] = *(const half8*)((Abuf) + offA[i_]); \
    _Pragma("unroll")                                               \
    for (int j_ = 0; j_ < 4; j_++) bf[j_] = *(const half8*)((Bbuf) + offB[j_]); \
    _Pragma("unroll")                                               \
    for (int i_ = 0; i_ < 4; i_++)                                  \
      _Pragma("unroll")                                             \
      for (int j_ = 0; j_ < 4; j_++)                                \
        acc[i_][j_] = __builtin_amdgcn_mfma_f32_16x16x32_f16(af[i_], bf[j_], acc[i_][j_], 0, 0, 0); \
  } while (0)

  // prologue: stage tile 0 into buffer 0
  STAGE_TO(As0, Bs0);
  __syncthreads();

  #pragma unroll
  for (int kk = 0; kk < 16; kk += 2) {
    if (kk + 1 < 16) STAGE_TO(As1, Bs1);    // prefetch tile kk+1
    COMPUTE_FROM(As0, Bs0);                 // compute tile kk
    __syncthreads();
    if (kk + 2 < 16) STAGE_TO(As0, Bs0);    // prefetch tile kk+2
    COMPUTE_FROM(As1, Bs1);                 // compute tile kk+1
    __syncthreads();
  }
#undef STAGE_TO
#undef COMPUTE_FROM

  // epilogue: per-row top-2 over this block's 128 cols.
  // 16-lane reduction via DPP row_ror (VALU) — rotation coverage sets are
  // disjoint each step, merge is exact and order-independent.
#define TOP2_DPP(CTRL) do {                                               \
    float o1 = dpp_rotf<CTRL>(v1);                                        \
    float o2 = dpp_rotf<CTRL>(v2);                                        \
    int   oi = dpp_roti<CTRL>(i1);                                        \
    if (o1 > v1 || (o1 == v1 && oi < i1)) { v2 = fmaxf(v1, o2); v1 = o1; i1 = oi; } \
    else                                  { v2 = fmaxf(v2, o1); }         \
  } while (0)

  const int h = w >> 1;
  #pragma unroll
  for (int i = 0; i < 4; i++) {
    #pragma unroll
    for (int r = 0; r < 4; r++) {
      float v1 = acc[i][0][r];
      int   i1 = col0 + n0 + c16;
      float v2 = -3.0e38f;
      #pragma unroll
      for (int j = 1; j < 4; j++) {
        float v = acc[i][j][r];
        int ix = col0 + n0 + j * 16 + c16;
        if (v > v1) { v2 = fmaxf(v2, v1); v1 = v; i1 = ix; }
        else        { v2 = fmaxf(v2, v); }
      }
      TOP2_DPP(0x121);   // row_ror:1
      TOP2_DPP(0x122);   // row_ror:2
      TOP2_DPP(0x124);   // row_ror:4
      TOP2_DPP(0x128);   // row_ror:8
      if (c16 == 0) {
        int rl = (w & 1) * 64 + i * 16 + quad * 4 + r;
        ev1[h][rl] = v1; ev2[h][rl] = v2; ei1[h][rl] = i1;
      }
    }
  }
#undef TOP2_DPP
  __syncthreads();
  if (t < 128) {
    float a1 = ev1[0][t], a2 = ev2[0][t]; int ai = ei1[0][t];
    float b1 = ev1[1][t], b2 = ev2[1][t]; int bi = ei1[1][t];
    float v1, v2; int i1;
    if (b1 > a1 || (b1 == a1 && bi < ai)) { v1 = b1; i1 = bi; v2 = fmaxf(a1, b2); }
    else                                  { v1 = a1; i1 = ai; v2 = fmaxf(a2, b1); }
    size_t o = (size_t)by * BATCH + row0 + t;
    c1v[o] = v1; c2v[o] = v2; c1i[o] = i1;
  }
}

// ---------- combine 64 tiles/row, margin test, flag list ----------
__global__ __launch_bounds__(256) void k_combine(const float* __restrict__ c1v,
                                                 const float* __restrict__ c2v,
                                                 const int* __restrict__ c1i,
                                                 int* __restrict__ idxs,
                                                 float* __restrict__ out3,
                                                 int* __restrict__ cnt,
                                                 int* __restrict__ frow,
                                                 int* __restrict__ nft,
                                                 int* __restrict__ ftile) {
  int row = blockIdx.x * 256 + threadIdx.x;
  float v1 = -3.0e38f, v2 = -3.0e38f; int i1 = 0;
  for (int ti = 0; ti < 64; ti++) {
    size_t o = (size_t)ti * BATCH + row;
    float a = c1v[o]; float a2 = c2v[o]; int ai = c1i[o];
    if (a > v1 || (a == v1 && ai < i1)) { v2 = fmaxf(v1, a2); v1 = a; i1 = ai; }
    else                                { v2 = fmaxf(v2, a); }
  }
  idxs[row] = i1;
  out3[row] = (float)i1;
  if (v1 - v2 < MARGIN) {
    int fid = atomicAdd(cnt, 1);
    if (fid < MAXFLAG) {
      frow[fid] = row;
      int jj = 0;
      for (int ti = 0; ti < 64; ti++) {
        if (c1v[(size_t)ti * BATCH + row] >= v1 - MARGIN && jj < MAXTILE)
          ftile[fid * MAXTILE + jj++] = ti;
      }
      nft[fid] = jj;
    }
  }
}

// ---------- exact fp32 refine of qualifying tiles for flagged rows ----------
__global__ __launch_bounds__(256) void k_refine(const float* __restrict__ z,
                                                const float* __restrict__ emb,
                                                const float* __restrict__ er,
                                                const int* __restrict__ cnt,
                                                const int* __restrict__ frow,
                                                const int* __restrict__ nft,
                                                const int* __restrict__ ftile,
                                                float* __restrict__ rval,
                                                int* __restrict__ ridx) {
  __shared__ float zl[512];
  __shared__ float rv[128];
  __shared__ int   ri[128];
  int fid = blockIdx.x;
  int m = cnt[0]; if (m > MAXFLAG) m = MAXFLAG;
  if (fid >= m) return;
  int t = threadIdx.x;
  int row = frow[fid];
  if (t < 128) ((float4*)zl)[t] = *(const float4*)(z + (size_t)row * 512 + t * 4);
  __syncthreads();
  int n = nft[fid];
  for (int jj = 0; jj < n; jj++) {
    int ti = ftile[fid * MAXTILE + jj];
    if (t < 128) {
      int code = ti * 128 + t;
      const float4* ep = (const float4*)(emb + (size_t)code * 512);
      const float4* zp = (const float4*)zl;
      float a0 = 0.f, a1 = 0.f, a2 = 0.f, a3 = 0.f;
      #pragma unroll 8
      for (int d = 0; d < 128; d++) {
        float4 e4 = ep[d]; float4 z4 = zp[d];
        a0 = fmaf(e4.x, z4.x, a0); a1 = fmaf(e4.y, z4.y, a1);
        a2 = fmaf(e4.z, z4.z, a2); a3 = fmaf(e4.w, z4.w, a3);
      }
      rv[t] = ((a0 + a1) + (a2 + a3)) * er[code];
      ri[t] = code;
    }
    __syncthreads();
    for (int off = 64; off > 0; off >>= 1) {
      if (t < off) {
        if (rv[t + off] > rv[t] || (rv[t + off] == rv[t] && ri[t + off] < ri[t])) {
          rv[t] = rv[t + off]; ri[t] = ri[t + off];
        }
      }
      __syncthreads();
    }
    if (t == 0) { rval[fid * MAXTILE + jj] = rv[0]; ridx[fid * MAXTILE + jj] = ri[0]; }
    __syncthreads();
  }
}

// ---------- merge refine results -> final index for flagged rows ----------
__global__ __launch_bounds__(256) void k_merge(const int* __restrict__ cnt,
                                               const int* __restrict__ frow,
                                               const int* __restrict__ nft,
                                               const float* __restrict__ rval,
                                               const int* __restrict__ ridx,
                                               int* __restrict__ idxs,
                                               float* __restrict__ out3) {
  int fid = blockIdx.x * 256 + threadIdx.x;
  int m = cnt[0]; if (m > MAXFLAG) m = MAXFLAG;
  if (fid >= m) return;
  int n = nft[fid];
  float bv = rval[fid * MAXTILE]; int bi = ridx[fid * MAXTILE];
  for (int jj = 1; jj < n; jj++) {
    float v = rval[fid * MAXTILE + jj]; int ix = ridx[fid * MAXTILE + jj];
    if (v > bv || (v == bv && ix < bi)) { bv = v; bi = ix; }
  }
  int row = frow[fid];
  idxs[row] = bi;
  out3[row] = (float)bi;
}

// ---------- counts from final indices (32768 int atomics) ----------
__global__ __launch_bounds__(256) void k_count(const int* __restrict__ idxs,
                                               int* __restrict__ counts) {
  int row = blockIdx.x * 256 + threadIdx.x;
  atomicAdd(&counts[idxs[row]], 1);
}

// ---------- exclusive prefix sum of counts -> offs, curs ----------
__global__ __launch_bounds__(256) void k_prefix(const int* __restrict__ counts,
                                                int* __restrict__ offs,
                                                int* __restrict__ curs) {
  __shared__ int ls[256];
  int t = threadIdx.x;
  int base = t * 32;
  int local[32];
  int s = 0;
  #pragma unroll
  for (int i = 0; i < 32; i++) { local[i] = s; s += counts[base + i]; }
  ls[t] = s;
  __syncthreads();
  for (int off = 1; off < 256; off <<= 1) {
    int add = (t >= off) ? ls[t - off] : 0;
    __syncthreads();
    ls[t] += add;
    __syncthreads();
  }
  int pre = (t == 0) ? 0 : ls[t - 1];
  #pragma unroll
  for (int i = 0; i < 32; i++) {
    int o = pre + local[i];
    offs[base + i] = o;
    curs[base + i] = o;
  }
  if (t == 255) offs[NCODE] = pre + s;
}

// ---------- scatter row ids into per-code buckets ----------
__global__ __launch_bounds__(256) void k_bucket(const int* __restrict__ idxs,
                                                int* __restrict__ curs,
                                                int* __restrict__ bucket) {
  int row = blockIdx.x * 256 + threadIdx.x;
  int idx = idxs[row];
  int pos = atomicAdd(&curs[idx], 1);
  bucket[pos] = row;
}

// ---------- cluster-size EMA + partial sums ----------
__global__ __launch_bounds__(256) void k_cluster(const float* __restrict__ cs,
                                                 const int* __restrict__ counts,
                                                 float* __restrict__ out6,
                                                 double* __restrict__ scal) {
  __shared__ double s1[256], s2[256];
  int t = threadIdx.x;
  int i = blockIdx.x * 256 + t;
  float cf = (float)counts[i];
  float ncs = DECAYF * cs[i] + OMDF * cf;
  out6[i] = ncs;
  s1[t] = (double)ncs;
  s2[t] = (double)cf;
  __syncthreads();
  for (int off = 128; off > 0; off >>= 1) {
    if (t < off) { s1[t] += s1[t + off]; s2[t] += s2[t + off]; }
    __syncthreads();
  }
  if (t == 0) { atomAddD(&scal[0], s1[0]); atomAddD(&scal[1], s2[0]); }
}

// ---------- embedding: bucket-sum + EMA + renormalize (no atomics) ----------
__global__ __launch_bounds__(128) void k_embed(const float* __restrict__ z,
                                               const float* __restrict__ ea,
                                               const int* __restrict__ offs,
                                               const int* __restrict__ bucket,
                                               const float* __restrict__ out6,
                                               const double* __restrict__ scal,
                                               float* __restrict__ out5,
                                               float* __restrict__ out7) {
  __shared__ float red[128];
  int k = blockIdx.x;
  int t = threadIdx.x;
  int beg = offs[k], end = offs[k + 1];
  float s0 = 0.f, s1 = 0.f, s2 = 0.f, s3 = 0.f;
  for (int j = beg; j < end; j++) {
    int r = bucket[j];
    float4 zv = *(const float4*)(z + (size_t)r * 512 + t * 4);
    s0 += zv.x; s1 += zv.y; s2 += zv.z; s3 += zv.w;
  }
  float n = (float)scal[0];
  float ncs = out6[k];
  float csn = (ncs + EPSF) / (n + (float)NCODE * EPSF) * n;
  size_t base = (size_t)k * 512 + t * 4;
  float4 eav = *(const float4*)(ea + base);
  float v[4];
  v[0] = (DECAYF * eav.x + OMDF * s0) / csn;
  v[1] = (DECAYF * eav.y + OMDF * s1) / csn;
  v[2] = (DECAYF * eav.z + OMDF * s2) / csn;
  v[3] = (DECAYF * eav.w + OMDF * s3) / csn;
  float ss = v[0]*v[0] + v[1]*v[1] + v[2]*v[2] + v[3]*v[3];
  red[t] = ss;
  __syncthreads();
  for (int off = 64; off > 0; off >>= 1) {
    if (t < off) red[t] += red[t + off];
    __syncthreads();
  }
  float inv = 1.0f / (sqrtf(red[0]) + EPSF);
  #pragma unroll
  for (int j = 0; j < 4; j++) {
    float nm = v[j] * inv;
    out5[base + j] = nm;
    out7[base + j] = nm * csn;
  }
}

// ---------- gather z_q -> out0 + MSE partials (no atomics) ----------
__global__ __launch_bounds__(256) void k_gather(
    const float* __restrict__ z, const float* __restrict__ emb,
    const int* __restrict__ idxs, float* __restrict__ out0,
    double* __restrict__ loss_part) {
  __shared__ float red[256];
  int t = threadIdx.x;
  int row = blockIdx.x * 8 + (t >> 5);
  int l = t & 31;
  int d0 = l * 16;
  int idx = idxs[row];
  const float4* zp = (const float4*)(z + (size_t)row * 512 + d0);
  const float4* ep = (const float4*)(emb + (size_t)idx * 512 + d0);
  float4* op = (float4*)(out0 + (size_t)row * 512 + d0);
  float ls = 0.f;
  #pragma unroll
  for (int q = 0; q < 4; q++) {
    float4 zv = zp[q];
    float4 ev = ep[q];
    op[q] = ev;  // z + (z_q - z) == z_q
    float dx = zv.x - ev.x, dy = zv.y - ev.y, dz = zv.z - ev.z, dw = zv.w - ev.w;
    ls += dx*dx + dy*dy + dz*dz + dw*dw;
  }
  red[t] = ls;
  __syncthreads();
  for (int off = 128; off > 0; off >>= 1) {
    if (t < off) red[t] += red[t + off];
    __syncthreads();
  }
  if (t == 0) loss_part[blockIdx.x] = (double)red[0];
}

// ---------- scalars ----------
__global__ __launch_bounds__(256) void k_scalars(const int* __restrict__ counts,
                                                 const double* __restrict__ scal,
                                                 const double* __restrict__ loss_part,
                                                 float* __restrict__ out1,
                                                 float* __restrict__ out2,
                                                 float* __restrict__ out4) {
  __shared__ double r1[256], r2[256], r3[256];
  int t = threadIdx.x;
  double csum = scal[1];
  double e1 = 0.0, e2 = 0.0, lsum = 0.0;
  for (int i = t; i < NCODE; i += 256) {
    double c = (double)counts[i];
    double p = c / csum;
    e1 += p * log(p + 1e-10);
    double a = c / (double)BATCH;
    e2 += a * log(a + 1e-10);
  }
  for (int i = t; i < NLOSSBLK; i += 256) lsum += loss_part[i];
  r1[t] = e1; r2[t] = e2; r3[t] = lsum;
  __syncthreads();
  for (int off = 128; off > 0; off >>= 1) {
    if (t < off) { r1[t] += r1[t+off]; r2[t] += r2[t+off]; r3[t] += r3[t+off]; }
    __syncthreads();
  }
  if (t == 0) {
    double entropy = -r1[0];
    double maxent = log((double)NCODE);
    double div = (maxent - entropy) / maxent;
    double mse = r3[0] / ((double)BATCH * (double)DIM);
    double vq = 0.3 * mse + mse + 0.001 * div;
    double perp = exp(-r2[0]);
    *out1 = (float)vq;
    *out2 = (float)perp;
    *out4 = (float)div;
  }
}

extern "C" void kernel_launch(void* const* d_in, const int* in_sizes, int n_in,
                              void* d_out, int out_size, void* d_ws, size_t ws_size,
                              hipStream_t stream) {
  const float* z   = (const float*)d_in[0];
  const float* emb = (const float*)d_in[1];
  const float* cs  = (const float*)d_in[2];
  const float* ea  = (const float*)d_in[3];

  float* out  = (float*)d_out;
  float* out0 = out;                    // z_q_st        [B*D]
  float* out1 = out + 16777216;         // vq_loss       [1]
  float* out2 = out + 16777217;         // perplexity    [1]
  float* out3 = out + 16777218;         // indices       [B]
  float* out4 = out + 16809986;         // diversity     [1]
  float* out5 = out + 16809987;         // new_embedding [K*D]
  float* out6 = out + 21004291;         // new_cluster   [K]
  float* out7 = out + 21012483;         // final_embed_avg [K*D]

  char* ws = (char*)d_ws;
  double* scal      = (double*)(ws + OFF_SCAL);
  int*    cnt       = (int*)   (ws + OFF_CNT);
  int*    counts    = (int*)   (ws + OFF_COUNTS);
  float*  er        = (float*) (ws + OFF_ER);
  int*    idxs      = (int*)   (ws + OFF_IDX);
  double* loss_part = (double*)(ws + OFF_LOSS);
  int*    frow      = (int*)   (ws + OFF_FROW);
  int*    nft       = (int*)   (ws + OFF_NFT);
  int*    ftile     = (int*)   (ws + OFF_FTILE);
  float*  rval      = (float*) (ws + OFF_RVAL);
  int*    ridx      = (int*)   (ws + OFF_RIDX);
  _Float16* eh      = (_Float16*)(ws + OFF_EH);

  // overlays:
  //  zh (fp16 z) on out5/out7 (dead until k_embed writes them)
  //  coarse candidates c1v/c2v/c1i on out0[0 .. 6291456)
  //  bucket structures on out0 tail [13500000 ..) — k_gather (which rewrites
  //  out0) runs after k_embed has consumed them
  _Float16* zh5 = (_Float16*)out5;
  _Float16* zh7 = (_Float16*)out7;
  float* c1v = out0;
  float* c2v = out0 + (size_t)64 * BATCH;
  int*   c1i = (int*)(out0 + (size_t)128 * BATCH);
  int*   offs   = (int*)(out0 + 13500000);   // [NCODE+1]
  int*   curs   = offs + NCODE + 64;         // [NCODE]
  int*   bucket = curs + NCODE;              // [BATCH]

  hipMemsetAsync(ws, 0, OFF_ER, stream);  // scal, cnt, counts

  k_prep_e<<<NCODE / 4, 256, 0, stream>>>(emb, er, eh);
  k_prep_z<<<8192, 256, 0, stream>>>(z, zh5, zh7);
  k_coarse<<<dim3(BATCH / 128, NCODE / 128), 256, 0, stream>>>(eh, zh5, zh7, c1v, c2v, c1i);
  k_combine<<<BATCH / 256, 256, 0, stream>>>(c1v, c2v, c1i, idxs, out3, cnt, frow, nft, ftile);
  k_refine<<<MAXFLAG, 256, 0, stream>>>(z, emb, er, cnt, frow, nft, ftile, rval, ridx);
  k_merge<<<MAXFLAG / 256, 256, 0, stream>>>(cnt, frow, nft, rval, ridx, idxs, out3);

  k_count<<<BATCH / 256, 256, 0, stream>>>(idxs, counts);
  k_cluster<<<NCODE / 256, 256, 0, stream>>>(cs, counts, out6, scal);
  k_prefix<<<1, 256, 0, stream>>>(counts, offs, curs);
  k_bucket<<<BATCH / 256, 256, 0, stream>>>(idxs, curs, bucket);
  k_embed<<<NCODE, 128, 0, stream>>>(z, ea, offs, bucket, out6, scal, out5, out7);

  k_gather<<<NLOSSBLK, 256, 0, stream>>>(z, emb, idxs, out0, loss_part);
  k_scalars<<<1, 256, 0, stream>>>(counts, scal, loss_part, out1, out2, out4);
}